// Round 3
// baseline (628.986 us; speedup 1.0000x reference)
//
#include <hip/hip_runtime.h>

// B=262144, C=6, P=64. Streaming elementwise SNN encoder step:
//   out = heaviside(beta[c]*mem + (x*W + b) - heaviside(mem-thr)*thr - thr)
// Numerics: __f{mul,add,sub}_rn forbid FMA contraction -> bit-identical to the
// numpy reference at the heaviside boundaries (R0/R1: absmax 0.0 -- keep).
//
// R2 theory: kernel was VMEM-instruction-bound (7 VMEM wave-instrs per float4
// of stream vs a copy's 2: mem/out/x/W/b + per-lane indexed BETA_C/THR_C
// rodata loads). Fix: W,b staged in LDS (VMEM->LDS pipe), beta/thr computed
// arithmetically. VMEM per float4 drops to 3 (mem ld, x ld, out st).

#define BB 262144
#define CC 6
#define PP 64
#define TOTAL4 ((BB * CC * PP) / 4)      // 25,165,824 float4s
#define UNROLL 4
#define NTHREADS (TOTAL4 / UNROLL)       // 6,291,456 threads

typedef float v4f __attribute__((ext_vector_type(4)));

__device__ __forceinline__ float spike_elem(float mv, float xv, float wv, float bv,
                                            float beta, float thr) {
    float cur   = __fadd_rn(__fmul_rn(xv, wv), bv);
    float rterm = (mv > thr) ? thr : 0.0f;                     // reset * thr
    float mn    = __fsub_rn(__fadd_rn(__fmul_rn(beta, mv), cur), rterm);
    return (mn > thr) ? 1.0f : 0.0f;
}

__global__ __launch_bounds__(256) void snn_encoder_kernel(
    const float* __restrict__ x,    // (B, C)
    const float* __restrict__ W,    // (C, P) = 384 floats
    const float* __restrict__ bias, // (C, P) = 384 floats
    const float* __restrict__ mem,  // (B, C, P)
    float* __restrict__ out)        // (B, C*P)
{
    __shared__ float lds_W[CC * PP];   // 1.5 KB
    __shared__ float lds_B[CC * PP];   // 1.5 KB

    // Cooperative one-shot stage of W and bias into LDS (96 float4s each).
    {
        const int lt = threadIdx.x;
        if (lt < 96) {
            ((v4f*)lds_W)[lt] = ((const v4f*)W)[lt];
        } else if (lt < 192) {
            ((v4f*)lds_B)[lt - 96] = ((const v4f*)bias)[lt - 96];
        }
    }
    __syncthreads();

    const int t = blockIdx.x * blockDim.x + threadIdx.x;   // < NTHREADS

    v4f   mv[UNROLL];
    float xv[UNROLL];
    int   j[UNROLL], cp[UNROLL], cidx[UNROLL];

    // Phase 1: issue the streaming loads (4 independent HBM float4 loads).
#pragma unroll
    for (int u = 0; u < UNROLL; ++u) {
        const int idx = t + u * NTHREADS;     // coalesced within each u
        j[u] = idx << 2;                      // flat element index
        const int r = j[u] >> 6;              // row = b*C + c  (== x index)
        const int p = j[u] & 63;
        const int c = r % 6;
        cp[u]   = c * PP + p;
        cidx[u] = c;

        mv[u] = __builtin_nontemporal_load((const v4f*)(mem + j[u]));
        xv[u] = x[r];
    }

    // Phase 2: LDS fragment reads + compute + streaming store.
#pragma unroll
    for (int u = 0; u < UNROLL; ++u) {
        const v4f wv = *(const v4f*)(lds_W + cp[u]);
        const v4f bv = *(const v4f*)(lds_B + cp[u]);
        const float beta = (cidx[u] & 1) ? 0.85f : 0.9f;   // BETA = {.9,.85,...}
        const float thr  = 1.0f;                           // THR all ones

        v4f o;
        o.x = spike_elem(mv[u].x, xv[u], wv.x, bv.x, beta, thr);
        o.y = spike_elem(mv[u].y, xv[u], wv.y, bv.y, beta, thr);
        o.z = spike_elem(mv[u].z, xv[u], wv.z, bv.z, beta, thr);
        o.w = spike_elem(mv[u].w, xv[u], wv.w, bv.w, beta, thr);
        __builtin_nontemporal_store(o, (v4f*)(out + j[u]));
    }
}

extern "C" void kernel_launch(void* const* d_in, const int* in_sizes, int n_in,
                              void* d_out, int out_size, void* d_ws, size_t ws_size,
                              hipStream_t stream) {
    const float* x    = (const float*)d_in[0];  // (B, C)
    const float* W    = (const float*)d_in[1];  // (C, P)
    const float* bias = (const float*)d_in[2];  // (C, P)
    const float* mem  = (const float*)d_in[3];  // (B, C, P)
    float* out = (float*)d_out;                 // (B, C*P)

    const int block = 256;
    const int grid  = NTHREADS / block;         // 24,576 blocks
    snn_encoder_kernel<<<grid, block, 0, stream>>>(x, W, bias, mem, out);
}

// Round 4
// 612.979 us; speedup vs baseline: 1.0261x; 1.0261x over previous
//
#include <hip/hip_runtime.h>

// B=262144, C=6, P=64. Streaming elementwise SNN encoder step:
//   out = heaviside(beta[c]*mem + (x*W + b) - heaviside(mem-thr)*thr - thr)
//
// Numerics: __f{mul,add,sub}_rn forbid FMA contraction -> bit-identical to the
// numpy reference at the heaviside boundaries (R0-R2: absmax 0.0 -- keep).
//
// History: R0 naive-float4 620.6us | R1 4x-MLP+NT 621.7 | R2 LDS+minVMEM 629.0.
// All within noise -> kernel is at its HBM floor (~130-150us of 813 MB traffic)
// and total dur_us is dominated by harness poison-fill (250us) + input-restore
// (~130us) fixed work. This round: best-measured R0 structure + the two
// zero-cost improvements (arithmetic beta/thr, NT on the no-reuse streams).

#define BB 262144
#define CC 6
#define PP 64
#define TOTAL4 ((BB * CC * PP) / 4)      // 25,165,824 float4s

typedef float v4f __attribute__((ext_vector_type(4)));

__device__ __forceinline__ float spike_elem(float mv, float xv, float wv, float bv,
                                            float beta, float thr) {
    float cur   = __fadd_rn(__fmul_rn(xv, wv), bv);
    float rterm = (mv > thr) ? thr : 0.0f;                     // reset * thr
    float mn    = __fsub_rn(__fadd_rn(__fmul_rn(beta, mv), cur), rterm);
    return (mn > thr) ? 1.0f : 0.0f;
}

__global__ __launch_bounds__(256) void snn_encoder_kernel(
    const float* __restrict__ x,    // (B, C)
    const float* __restrict__ W,    // (C, P)
    const float* __restrict__ bias, // (C, P)
    const float* __restrict__ mem,  // (B, C, P)
    float* __restrict__ out)        // (B, C*P)
{
    const int tid = blockIdx.x * blockDim.x + threadIdx.x;
    if (tid >= TOTAL4) return;

    const int j = tid << 2;          // flat element index
    const int r = j >> 6;            // row = b*C + c  (== flat x index)
    const int p = j & 63;
    const int c = r % 6;

    const float xv   = x[r];
    const float beta = (c & 1) ? 0.85f : 0.9f;   // BETA = {.9,.85,.9,.85,.9,.85}
    const float thr  = 1.0f;                     // THR all ones

    const v4f wv = *(const v4f*)(W    + c * PP + p);
    const v4f bv = *(const v4f*)(bias + c * PP + p);
    const v4f mv = __builtin_nontemporal_load((const v4f*)(mem + j));

    v4f o;
    o.x = spike_elem(mv.x, xv, wv.x, bv.x, beta, thr);
    o.y = spike_elem(mv.y, xv, wv.y, bv.y, beta, thr);
    o.z = spike_elem(mv.z, xv, wv.z, bv.z, beta, thr);
    o.w = spike_elem(mv.w, xv, wv.w, bv.w, beta, thr);

    __builtin_nontemporal_store(o, (v4f*)(out + j));
}

extern "C" void kernel_launch(void* const* d_in, const int* in_sizes, int n_in,
                              void* d_out, int out_size, void* d_ws, size_t ws_size,
                              hipStream_t stream) {
    const float* x    = (const float*)d_in[0];  // (B, C)
    const float* W    = (const float*)d_in[1];  // (C, P)
    const float* bias = (const float*)d_in[2];  // (C, P)
    const float* mem  = (const float*)d_in[3];  // (B, C, P)
    float* out = (float*)d_out;                 // (B, C*P)

    const int block = 256;
    const int grid  = (TOTAL4 + block - 1) / block;   // 98,304 blocks
    snn_encoder_kernel<<<grid, block, 0, stream>>>(x, W, bias, mem, out);
}